// Round 15
// baseline (680.900 us; speedup 1.0000x reference)
//
#include <hip/hip_runtime.h>
#include <math.h>

#define H 128
#define NG 50
#define TB 4096
#define DMAX 12.0f
#define LOG2F_ 0.69314718055994531f

typedef __attribute__((ext_vector_type(8))) short bfrag8;
typedef __attribute__((ext_vector_type(4))) float f32x4;
typedef __attribute__((ext_vector_type(8))) unsigned short u16x8;

__device__ __forceinline__ float sspf(float x) {
    float xc = fminf(x, 60.f);
    float r = __logf(1.f + __expf(xc)) - LOG2F_;
    return r + fmaxf(x - 60.f, 0.f);
}
__device__ __forceinline__ float bf2f(unsigned short u) {
    union { unsigned int i; float f; } c; c.i = ((unsigned int)u) << 16; return c.f;
}
__device__ __forceinline__ unsigned short f2bf(float f) {
    union { float f; unsigned int i; } c; c.f = f;
    unsigned int r = c.i + 0x7fffu + ((c.i >> 16) & 1u);
    return (unsigned short)(r >> 16);
}

// transpose+cast the 18 layer weight matrices: Wt[mat][n][k] bf16 from W[k][n] fp32
__global__ void prep_w_kernel(const float* __restrict__ linW, const float* __restrict__ vW1,
                              const float* __restrict__ vW2, unsigned short* __restrict__ Wt) {
    int mat = blockIdx.x >> 4;
    int local = (blockIdx.x & 15) * 256 + threadIdx.x;
    int nrow = local >> 5;
    int k4 = local & 31;
    const float* src = (mat < 6) ? linW + mat * 16384
                     : (mat < 12) ? vW1 + (mat - 6) * 16384
                                  : vW2 + (mat - 12) * 16384;
    ushort4 o;
    o.x = f2bf(src[(k4 * 4 + 0) * H + nrow]);
    o.y = f2bf(src[(k4 * 4 + 1) * H + nrow]);
    o.z = f2bf(src[(k4 * 4 + 2) * H + nrow]);
    o.w = f2bf(src[(k4 * 4 + 3) * H + nrow]);
    *(ushort4*)(Wt + mat * 16384 + nrow * H + k4 * 4) = o;
}

// transpose+cast readout W1: Ut[c][k] bf16 from u_W1[k][c] fp32 (128x64)
__global__ void prep_u_kernel(const float* __restrict__ uW1, unsigned short* __restrict__ Ut) {
    int idx = blockIdx.x * 256 + threadIdx.x;
    int c = idx >> 7, k = idx & 127;
    Ut[c * H + k] = f2bf(uW1[k * 64 + c]);
}

// per-edge distance -> rounded table index; histogram of destination degree
__global__ void edge_dist_kernel(const int* __restrict__ ei, const float* __restrict__ pos,
                                 int* __restrict__ eint, int* __restrict__ deg,
                                 int E_, float inv_step) {
    int e = blockIdx.x * 256 + threadIdx.x;
    if (e >= E_) return;
    int j = ei[e];
    int i = ei[E_ + e];
    float dx = pos[j*3+0] - pos[i*3+0];
    float dy = pos[j*3+1] - pos[i*3+1];
    float dz = pos[j*3+2] - pos[i*3+2];
    float d = sqrtf(dx*dx + dy*dy + dz*dz);
    int ir = (int)(d * inv_step + 0.5f);
    eint[e] = min(ir, TB - 1);
    atomicAdd(&deg[i], 1);
}

// counting-sort phase 1: per-block LDS histogram; LDS-atomic return = local rank.
__global__ void hist_pb_kernel(const int* __restrict__ deg, int* __restrict__ bhist,
                               int* __restrict__ lrank, int n, int nb) {
    __shared__ int h[64];
    const int tid = threadIdx.x;
    if (tid < 64) h[tid] = 0;
    __syncthreads();
    int i = blockIdx.x * 256 + tid;
    if (i < n) lrank[i] = atomicAdd(&h[min(deg[i], 63)], 1);
    __syncthreads();
    if (tid < 64) bhist[tid * nb + blockIdx.x] = h[tid];
}

// counting-sort phase 2: one wave; per-bucket cross-block scan + descending bases
__global__ void scanb_kernel(int* __restrict__ bhist, int* __restrict__ base, int nb) {
    const int b = threadIdx.x;
    int run = 0;
    for (int k0 = 0; k0 < nb; k0 += 8) {
        int v[8];
        #pragma unroll
        for (int u = 0; u < 8; ++u)
            v[u] = (k0 + u < nb) ? bhist[b * nb + k0 + u] : 0;
        #pragma unroll
        for (int u = 0; u < 8; ++u) {
            int t = v[u];
            if (k0 + u < nb) bhist[b * nb + k0 + u] = run;
            run += t;
        }
    }
    int incl = run;
    #pragma unroll
    for (int off = 1; off < 64; off <<= 1) {
        int y = __shfl_up(incl, off, 64);
        if (b >= off) incl += y;
    }
    int total = __shfl(incl, 63, 64);
    base[b] = total - incl;
}

// counting-sort phase 3: pos = base[d] + bofs[blk][d] + lrank[i]. No atomics.
__global__ void place_kernel(const int* __restrict__ deg, const int* __restrict__ bhist,
                             const int* __restrict__ base, const int* __restrict__ lrank,
                             int* __restrict__ perm, int* __restrict__ iperm,
                             int* __restrict__ sdeg, int n, int nb) {
    int i = blockIdx.x * 256 + threadIdx.x;
    if (i >= n) return;
    int d = deg[i];
    int b = min(d, 63);
    int pos = base[b] + bhist[b * nb + blockIdx.x] + lrank[i];
    perm[pos] = i;
    iperm[i] = pos;
    sdeg[pos] = d;
}

// parallel scan phase A: per-block (1024-chunk) sum of sdeg
__global__ void scanA_kernel(const int* __restrict__ sdeg, int* __restrict__ bsum, int n) {
    __shared__ int ws[16];
    int tid = threadIdx.x;
    int idx = blockIdx.x * 1024 + tid;
    int x = (idx < n) ? sdeg[idx] : 0;
    #pragma unroll
    for (int off = 32; off > 0; off >>= 1) x += __shfl_xor(x, off, 64);
    int lane = tid & 63, wid = tid >> 6;
    if (lane == 0) ws[wid] = x;
    __syncthreads();
    if (tid == 0) {
        int s = 0;
        #pragma unroll
        for (int i = 0; i < 16; ++i) s += ws[i];
        bsum[blockIdx.x] = s;
    }
}

// phase C: local scan + self-computed block prefix -> row_ptr, cursor
__global__ void scanC_kernel(const int* __restrict__ sdeg, const int* __restrict__ bsum,
                             int* __restrict__ row_ptr, int* __restrict__ cursor, int n) {
    __shared__ int wsum[16];
    __shared__ int boff_s;
    int tid = threadIdx.x;
    int idx = blockIdx.x * 1024 + tid;
    int lane = tid & 63, wid = tid >> 6;
    if (tid == 0) {
        int s = 0;
        for (int b = 0; b < (int)blockIdx.x; ++b) s += bsum[b];
        boff_s = s;
    }
    int x = (idx < n) ? sdeg[idx] : 0;
    int v = x;
    #pragma unroll
    for (int off = 1; off < 64; off <<= 1) {
        int y = __shfl_up(v, off, 64);
        if (lane >= off) v += y;
    }
    if (lane == 63) wsum[wid] = v;
    __syncthreads();
    int woff = 0;
    for (int w = 0; w < wid; ++w) woff += wsum[w];
    int excl = boff_s + woff + v - x;
    if (idx < n) { row_ptr[idx] = excl; cursor[idx] = excl; }
    if (idx == n - 1) row_ptr[n] = excl + x;
}

// scatter edges into CSR slots (permuted node space), packed (src, tbl-index)
__global__ void csr_fill_kernel(const int* __restrict__ ei, const int* __restrict__ eint,
                                const int* __restrict__ iperm,
                                int* __restrict__ cursor, int2* __restrict__ epack, int E_) {
    int e = blockIdx.x * 256 + threadIdx.x;
    if (e >= E_) return;
    int pi = iperm[ei[E_ + e]];
    int slot = atomicAdd(&cursor[pi], 1);
    epack[slot] = make_int2(iperm[ei[e]], eint[e]);
}

// all 6 layers' filter tables. Block = 32 d-rows of one layer. TB=4096 -> 768 blocks.
__global__ __launch_bounds__(256) void table_all_kernel(
        const float* __restrict__ mW1, const float* __restrict__ mb1,
        const float* __restrict__ mW2, const float* __restrict__ mb2,
        unsigned short* __restrict__ tbl, float step) {
    __shared__ float gs[32][52];
    __shared__ float h1s[32][132];
    const int l = blockIdx.x >> 7;
    const int r0 = (blockIdx.x & 127) * 32;
    const float* W1 = mW1 + l * NG * H;
    const float* b1 = mb1 + l * H;
    const float* W2 = mW2 + l * H * H;
    const float* b2 = mb2 + l * H;
    const int tid = threadIdx.x;
    const float offstep = 10.0f / 49.0f;
    const float coeff = -0.5f / (offstep * offstep);

    for (int idx = tid; idx < 32 * NG; idx += 256) {
        int r = idx / NG, q = idx - r * NG;
        float dd = (r0 + r) * step - q * offstep;
        gs[r][q] = __expf(coeff * dd * dd);
    }
    __syncthreads();

    const int c = tid & 127, rb = (tid >> 7) * 16;
    {
        float acc[16];
        float bv = b1[c];
        #pragma unroll
        for (int r = 0; r < 16; ++r) acc[r] = bv;
        for (int q = 0; q < NG; ++q) {
            float w = W1[q * H + c];
            #pragma unroll
            for (int r = 0; r < 16; ++r) acc[r] = fmaf(gs[rb + r][q], w, acc[r]);
        }
        #pragma unroll
        for (int r = 0; r < 16; ++r) h1s[rb + r][c] = sspf(acc[r]);
    }
    __syncthreads();
    {
        float acc[16];
        float bv = b2[c];
        #pragma unroll
        for (int r = 0; r < 16; ++r) acc[r] = bv;
        for (int f4 = 0; f4 < 32; ++f4) {
            float w0 = W2[(f4 * 4 + 0) * H + c];
            float w1 = W2[(f4 * 4 + 1) * H + c];
            float w2 = W2[(f4 * 4 + 2) * H + c];
            float w3 = W2[(f4 * 4 + 3) * H + c];
            #pragma unroll
            for (int r = 0; r < 16; ++r) {
                float4 h = *(const float4*)&h1s[rb + r][f4 * 4];
                acc[r] = fmaf(h.x, w0, acc[r]);
                acc[r] = fmaf(h.y, w1, acc[r]);
                acc[r] = fmaf(h.z, w2, acc[r]);
                acc[r] = fmaf(h.w, w3, acc[r]);
            }
        }
        #pragma unroll
        for (int r = 0; r < 16; ++r) {
            float d = (r0 + rb + r) * step;
            float C = 0.5f * (cosf(d * 0.31415926535897932f) + 1.0f);
            tbl[(size_t)l * TB * H + (size_t)(r0 + rb + r) * H + c] = f2bf(acc[r] * C);
        }
    }
}

// Fused embed + layer-0 lin GEMM (permuted rows)
__global__ __launch_bounds__(256) void gemm_rs_embed_kernel(
        const int* __restrict__ z, const int* __restrict__ perm,
        const float* __restrict__ emb, const unsigned short* __restrict__ Wt,
        unsigned short* __restrict__ vbf, unsigned short* __restrict__ outB, int n) {
    __shared__ unsigned short t1s[4 * 16 * H];
    const int tid = threadIdx.x;
    const int task = blockIdx.x * 4 + (tid >> 6);
    const int lane = tid & 63, l16 = lane & 15, quad = lane >> 4;
    char* t1w = (char*)(t1s + (tid >> 6) * (16 * H));
    const size_t r0 = (size_t)task * 16;
    const int p = (int)r0 + l16;
    if (p >= n) return;

    const float* erow = emb + (size_t)z[perm[p]] * H;
    bfrag8 af[4];
    #pragma unroll
    for (int kc = 0; kc < 4; ++kc) {
        const int c0 = (kc * 4 + quad) * 8;
        float4 a = *(const float4*)(erow + c0);
        float4 b = *(const float4*)(erow + c0 + 4);
        u16x8 o;
        o[0] = f2bf(a.x); o[1] = f2bf(a.y); o[2] = f2bf(a.z); o[3] = f2bf(a.w);
        o[4] = f2bf(b.x); o[5] = f2bf(b.y); o[6] = f2bf(b.z); o[7] = f2bf(b.w);
        *(u16x8*)(vbf + (size_t)p * H + c0) = o;
        af[kc] = (bfrag8)o;
    }

    #pragma unroll
    for (int ch = 0; ch < 2; ++ch) {
        bfrag8 bf[4][4];
        f32x4 acc[4];
        #pragma unroll
        for (int nt = 0; nt < 4; ++nt) {
            #pragma unroll
            for (int kc = 0; kc < 4; ++kc)
                bf[nt][kc] = *(const bfrag8*)(Wt + (size_t)(ch * 64 + nt * 16 + l16) * H
                                              + (kc * 4 + quad) * 8);
            acc[nt] = (f32x4){0.f, 0.f, 0.f, 0.f};
        }
        #pragma unroll
        for (int nt = 0; nt < 4; ++nt)
            #pragma unroll
            for (int kc = 0; kc < 4; ++kc)
                acc[nt] = __builtin_amdgcn_mfma_f32_16x16x32_bf16(af[kc], bf[nt][kc],
                                                                  acc[nt], 0, 0, 0);
        #pragma unroll
        for (int nt = 0; nt < 4; ++nt) {
            const int col = ch * 64 + nt * 16 + l16;
            const int chunk = col >> 3;
            #pragma unroll
            for (int reg = 0; reg < 4; ++reg) {
                int m = quad * 4 + reg;
                *(unsigned short*)(t1w + m * 256 + ((chunk ^ m) * 16) + (col & 7) * 2)
                    = f2bf(acc[nt][reg]);
            }
        }
    }
    asm volatile("s_waitcnt lgkmcnt(0)" ::: "memory");
    {
        const int m = lane >> 2, cg = lane & 3;
        const size_t gr = r0 + m;
        #pragma unroll
        for (int c4 = 0; c4 < 4; ++c4) {
            int chunk = cg * 4 + c4;
            u16x8 d8 = *(const u16x8*)(t1w + m * 256 + ((chunk ^ m) * 16));
            *(u16x8*)(outB + gr * H + cg * 32 + c4 * 8) = d8;
        }
    }
}

// Merged per-layer kernel (permuted space). W3t==nullptr => fused readout layer.
__global__ __launch_bounds__(256, 4) void layer_kernel(
        const int* __restrict__ row_ptr, const int2* __restrict__ epack,
        const unsigned short* __restrict__ tbl, const unsigned short* __restrict__ vlin,
        const unsigned short* __restrict__ W1t, const unsigned short* __restrict__ W2t,
        const unsigned short* __restrict__ W3t,
        const float* __restrict__ b1, const float* __restrict__ b2,
        unsigned short* __restrict__ vbf, unsigned short* __restrict__ outNext,
        const int* __restrict__ batch, const int* __restrict__ perm,
        const unsigned short* __restrict__ Ut, const float* __restrict__ ub1,
        const float* __restrict__ uW2, const float* __restrict__ ub2,
        float* __restrict__ partial, int n) {
    __shared__ unsigned short bufA[16 * H];
    __shared__ unsigned short bufB[16 * H];
    __shared__ float hsum[16];
    __shared__ float gbin[64];
    const int tid = threadIdx.x;
    const int w = tid >> 6, lane = tid & 63;
    const int r0 = blockIdx.x * 16;
    const int l16 = lane & 15, quad = lane >> 4;

    const int rrow = tid >> 4, rcolg = tid & 15;
    const int rnode = r0 + rrow;
    u16x8 rv = {0,0,0,0,0,0,0,0};
    if (rnode < n) rv = *(const u16x8*)(vbf + (size_t)rnode * H + rcolg * 8);

    // ---- phase G: gather (nearest-neighbor table, 8-edge unroll) ----
    {
        const int nd = w * 4 + (lane >> 4);
        const int sub = lane & 15;
        const int node = r0 + nd;
        float acc[8] = {0.f, 0.f, 0.f, 0.f, 0.f, 0.f, 0.f, 0.f};
        if (node < n) {
            const int s = row_ptr[node], e_end = row_ptr[node + 1];
            int k = s;
            for (; k + 8 <= e_end; k += 8) {
                int2 ep[8];
                #pragma unroll
                for (int e = 0; e < 8; ++e) ep[e] = epack[k + e];
                u16x8 wv[8], vj[8];
                #pragma unroll
                for (int e = 0; e < 8; ++e) {
                    wv[e] = *(const u16x8*)(tbl + (size_t)ep[e].y * H + sub * 8);
                    vj[e] = *(const u16x8*)(vlin + (size_t)ep[e].x * H + sub * 8);
                }
                #pragma unroll
                for (int e = 0; e < 8; ++e)
                    #pragma unroll
                    for (int c = 0; c < 8; ++c)
                        acc[c] = fmaf(bf2f(vj[e][c]), bf2f(wv[e][c]), acc[c]);
            }
            for (; k < e_end; ++k) {
                int2 ep = epack[k];
                u16x8 wv = *(const u16x8*)(tbl + (size_t)ep.y * H + sub * 8);
                u16x8 vj = *(const u16x8*)(vlin + (size_t)ep.x * H + sub * 8);
                #pragma unroll
                for (int c = 0; c < 8; ++c)
                    acc[c] = fmaf(bf2f(vj[c]), bf2f(wv[c]), acc[c]);
            }
        }
        u16x8 o;
        #pragma unroll
        for (int c = 0; c < 8; ++c) o[c] = f2bf(acc[c]);
        *(u16x8*)((char*)bufA + nd * 256 + ((sub ^ nd) * 16)) = o;
    }
    __syncthreads();

    // ---- phase 1: t1 cols w*32..+31 ----
    {
        bfrag8 af[4];
        #pragma unroll
        for (int kc = 0; kc < 4; ++kc)
            af[kc] = *(const bfrag8*)((char*)bufA + l16 * 256 + (((kc * 4 + quad) ^ l16) * 16));
        #pragma unroll
        for (int nt2 = 0; nt2 < 2; ++nt2) {
            const int colt = w * 32 + nt2 * 16;
            bfrag8 bf[4];
            #pragma unroll
            for (int kc = 0; kc < 4; ++kc)
                bf[kc] = *(const bfrag8*)(W1t + (size_t)(colt + l16) * H + (kc * 4 + quad) * 8);
            f32x4 acc = (f32x4){0.f, 0.f, 0.f, 0.f};
            #pragma unroll
            for (int kc = 0; kc < 4; ++kc)
                acc = __builtin_amdgcn_mfma_f32_16x16x32_bf16(af[kc], bf[kc], acc, 0, 0, 0);
            const int f = colt + l16;
            const float bv = b1[f];
            const int chunk = f >> 3;
            #pragma unroll
            for (int reg = 0; reg < 4; ++reg) {
                int mr = quad * 4 + reg;
                *(unsigned short*)((char*)bufB + mr * 256 + ((chunk ^ mr) * 16) + (f & 7) * 2)
                    = f2bf(sspf(acc[reg] + bv));
            }
        }
    }
    __syncthreads();

    // ---- phase 2: delta cols w*32..+31 ----
    {
        bfrag8 af[4];
        #pragma unroll
        for (int kc = 0; kc < 4; ++kc)
            af[kc] = *(const bfrag8*)((char*)bufB + l16 * 256 + (((kc * 4 + quad) ^ l16) * 16));
        #pragma unroll
        for (int nt2 = 0; nt2 < 2; ++nt2) {
            const int colt = w * 32 + nt2 * 16;
            bfrag8 bf[4];
            #pragma unroll
            for (int kc = 0; kc < 4; ++kc)
                bf[kc] = *(const bfrag8*)(W2t + (size_t)(colt + l16) * H + (kc * 4 + quad) * 8);
            f32x4 acc = (f32x4){0.f, 0.f, 0.f, 0.f};
            #pragma unroll
            for (int kc = 0; kc < 4; ++kc)
                acc = __builtin_amdgcn_mfma_f32_16x16x32_bf16(af[kc], bf[kc], acc, 0, 0, 0);
            const int col = colt + l16;
            const float bv = b2[col];
            const int chunk = col >> 3;
            #pragma unroll
            for (int reg = 0; reg < 4; ++reg) {
                int mr = quad * 4 + reg;
                *(unsigned short*)((char*)bufA + mr * 256 + ((chunk ^ mr) * 16) + (col & 7) * 2)
                    = f2bf(acc[reg] + bv);
            }
        }
    }
    __syncthreads();

    // ---- phase R: vnew = rv + delta -> vbf, stash -> bufB; zero readout bins ----
    {
        u16x8 d8 = *(const u16x8*)((char*)bufA + rrow * 256 + ((rcolg ^ rrow) * 16));
        u16x8 ob;
        #pragma unroll
        for (int c = 0; c < 8; ++c) ob[c] = f2bf(bf2f(rv[c]) + bf2f(d8[c]));
        if (rnode < n) *(u16x8*)(vbf + (size_t)rnode * H + rcolg * 8) = ob;
        *(u16x8*)((char*)bufB + rrow * 256 + ((rcolg ^ rrow) * 16)) = ob;
        if (tid < 16) hsum[tid] = 0.f;
        if (tid < 64) gbin[tid] = 0.f;
    }
    __syncthreads();

    if (W3t) {
        // ---- phase 3: vlin_next cols w*32..+31 ----
        bfrag8 af[4];
        #pragma unroll
        for (int kc = 0; kc < 4; ++kc)
            af[kc] = *(const bfrag8*)((char*)bufB + l16 * 256 + (((kc * 4 + quad) ^ l16) * 16));
        #pragma unroll
        for (int nt2 = 0; nt2 < 2; ++nt2) {
            const int colt = w * 32 + nt2 * 16;
            bfrag8 bf[4];
            #pragma unroll
            for (int kc = 0; kc < 4; ++kc)
                bf[kc] = *(const bfrag8*)(W3t + (size_t)(colt + l16) * H + (kc * 4 + quad) * 8);
            f32x4 acc = (f32x4){0.f, 0.f, 0.f, 0.f};
            #pragma unroll
            for (int kc = 0; kc < 4; ++kc)
                acc = __builtin_amdgcn_mfma_f32_16x16x32_bf16(af[kc], bf[kc], acc, 0, 0, 0);
            const int col = colt + l16;
            const int chunk = col >> 3;
            #pragma unroll
            for (int reg = 0; reg < 4; ++reg) {
                int mr = quad * 4 + reg;
                *(unsigned short*)((char*)bufA + mr * 256 + ((chunk ^ mr) * 16) + (col & 7) * 2)
                    = f2bf(acc[reg]);
            }
        }
        __syncthreads();
        u16x8 d8 = *(const u16x8*)((char*)bufA + rrow * 256 + ((rcolg ^ rrow) * 16));
        if (rnode < n) *(u16x8*)(outNext + (size_t)rnode * H + rcolg * 8) = d8;
    } else {
        // ---- fused readout: h = ssp(vnew@Ut^T + ub1)·uW2, binned per graph ----
        bfrag8 af[4];
        #pragma unroll
        for (int kc = 0; kc < 4; ++kc)
            af[kc] = *(const bfrag8*)((char*)bufB + l16 * 256 + (((kc * 4 + quad) ^ l16) * 16));
        const int colu = w * 16 + l16;
        bfrag8 bfu[4];
        #pragma unroll
        for (int kc = 0; kc < 4; ++kc)
            bfu[kc] = *(const bfrag8*)(Ut + (size_t)colu * H + (kc * 4 + quad) * 8);
        f32x4 acc = (f32x4){0.f, 0.f, 0.f, 0.f};
        #pragma unroll
        for (int kc = 0; kc < 4; ++kc)
            acc = __builtin_amdgcn_mfma_f32_16x16x32_bf16(af[kc], bfu[kc], acc, 0, 0, 0);
        const float b1v = ub1[colu], w2v = uW2[colu];
        #pragma unroll
        for (int reg = 0; reg < 4; ++reg) {
            float s = sspf(acc[reg] + b1v) * w2v;
            s += __shfl_xor(s, 1, 64);
            s += __shfl_xor(s, 2, 64);
            s += __shfl_xor(s, 4, 64);
            s += __shfl_xor(s, 8, 64);
            if (l16 == 0) atomicAdd(&hsum[quad * 4 + reg], s);
        }
        __syncthreads();
        if (tid < 16) {
            int node = r0 + tid;
            if (node < n) atomicAdd(&gbin[batch[perm[node]]], hsum[tid] + ub2[0]);
        }
        __syncthreads();
        if (tid < 64) partial[(size_t)blockIdx.x * 64 + tid] = gbin[tid];
    }
}

// readout stage 2: out[g] = sum over nchunk blocks of partial[b][g]
__global__ void readout2_kernel(const float* __restrict__ partial, float* __restrict__ out,
                                int nb) {
    __shared__ float red[1024];
    const int tid = threadIdx.x;
    const int g = tid & 63, q = tid >> 6;    // 16 q-groups
    float acc = 0.f;
    for (int b = q; b < nb; b += 16) acc += partial[(size_t)b * 64 + g];
    red[tid] = acc;
    __syncthreads();
    if (tid < 64) {
        float s = 0.f;
        #pragma unroll
        for (int k = 0; k < 16; ++k) s += red[k * 64 + tid];
        out[tid] = s;
    }
}

extern "C" void kernel_launch(void* const* d_in, const int* in_sizes, int n_in,
                              void* d_out, int out_size, void* d_ws, size_t ws_size,
                              hipStream_t stream) {
    const int*   z       = (const int*)d_in[0];
    const float* pos     = (const float*)d_in[1];
    const int*   batch   = (const int*)d_in[2];
    const int*   ei      = (const int*)d_in[3];
    const float* emb     = (const float*)d_in[4];
    const float* lin_W   = (const float*)d_in[5];
    const float* mlp_W1  = (const float*)d_in[6];
    const float* mlp_b1  = (const float*)d_in[7];
    const float* mlp_W2  = (const float*)d_in[8];
    const float* mlp_b2  = (const float*)d_in[9];
    const float* v_W1    = (const float*)d_in[10];
    const float* v_b1    = (const float*)d_in[11];
    const float* v_W2    = (const float*)d_in[12];
    const float* v_b2    = (const float*)d_in[13];
    const float* u_W1    = (const float*)d_in[14];
    const float* u_b1    = (const float*)d_in[15];
    const float* u_W2    = (const float*)d_in[16];
    const float* u_b2    = (const float*)d_in[17];
    const int n  = in_sizes[0];
    const int E_ = in_sizes[3] / 2;
    float* out = (float*)d_out;

    char* wp = (char*)d_ws;
    auto alloc = [&](size_t bytes) { char* p = wp; wp += (bytes + 255) & ~(size_t)255; return p; };
    const int NB1K = (n + 1023) / 1024;
    const int NB256 = (n + 255) / 256;
    const int nchunk = (n + 15) / 16;
    unsigned short* vbf     = (unsigned short*)alloc((size_t)n * H * 2);
    unsigned short* vlinA   = (unsigned short*)alloc((size_t)n * H * 2);
    unsigned short* vlinB   = (unsigned short*)alloc((size_t)n * H * 2);
    unsigned short* WtAll   = (unsigned short*)alloc((size_t)18 * H * H * 2);
    unsigned short* Ut      = (unsigned short*)alloc((size_t)64 * H * 2);
    unsigned short* tbl     = (unsigned short*)alloc((size_t)6 * TB * H * 2);
    int*   eint    = (int*)alloc((size_t)E_ * 4);
    int2*  epack   = (int2*)alloc((size_t)E_ * 8);
    int*   deg     = (int*)alloc((size_t)n * 4);
    int*   sdeg    = (int*)alloc((size_t)n * 4);
    int*   perm    = (int*)alloc((size_t)n * 4);
    int*   iperm   = (int*)alloc((size_t)n * 4);
    int*   lrank   = (int*)alloc((size_t)n * 4);
    int*   row_ptr = (int*)alloc((size_t)(n + 1) * 4);
    int*   cursor  = (int*)alloc((size_t)n * 4);
    int*   bsum    = (int*)alloc((size_t)NB1K * 4);
    int*   bhist   = (int*)alloc((size_t)64 * NB256 * 4);
    int*   base    = (int*)alloc(64 * 4);
    float* partial = (float*)alloc((size_t)nchunk * 64 * 4);

    const float step = DMAX / TB;
    hipMemsetAsync(deg, 0, (size_t)n * 4, stream);

    prep_w_kernel<<<288, 256, 0, stream>>>(lin_W, v_W1, v_W2, WtAll);
    prep_u_kernel<<<32, 256, 0, stream>>>(u_W1, Ut);
    table_all_kernel<<<768, 256, 0, stream>>>(mlp_W1, mlp_b1, mlp_W2, mlp_b2, tbl, step);
    edge_dist_kernel<<<(E_ + 255) / 256, 256, 0, stream>>>(ei, pos, eint, deg, E_, 1.0f / step);
    hist_pb_kernel<<<NB256, 256, 0, stream>>>(deg, bhist, lrank, n, NB256);
    scanb_kernel<<<1, 64, 0, stream>>>(bhist, base, NB256);
    place_kernel<<<NB256, 256, 0, stream>>>(deg, bhist, base, lrank, perm, iperm, sdeg, n, NB256);
    scanA_kernel<<<NB1K, 1024, 0, stream>>>(sdeg, bsum, n);
    scanC_kernel<<<NB1K, 1024, 0, stream>>>(sdeg, bsum, row_ptr, cursor, n);
    csr_fill_kernel<<<(E_ + 255) / 256, 256, 0, stream>>>(ei, eint, iperm, cursor, epack, E_);

    const int GRS = (nchunk + 3) / 4;
    gemm_rs_embed_kernel<<<GRS, 256, 0, stream>>>(z, perm, emb, WtAll, vbf, vlinA, n);
    unsigned short* cur = vlinA;
    unsigned short* nxt = vlinB;
    for (int l = 0; l < 6; ++l) {
        const unsigned short* W3t = (l < 5) ? (WtAll + (l + 1) * H * H) : nullptr;
        layer_kernel<<<nchunk, 256, 0, stream>>>(row_ptr, epack,
                                                 tbl + (size_t)l * TB * H, cur,
                                                 WtAll + (6 + l) * H * H,
                                                 WtAll + (12 + l) * H * H, W3t,
                                                 v_b1 + l * H, v_b2 + l * H,
                                                 vbf, nxt,
                                                 batch, perm, Ut, u_b1, u_W2, u_b2,
                                                 partial, n);
        unsigned short* tmp = cur; cur = nxt; nxt = tmp;
    }
    readout2_kernel<<<1, 1024, 0, stream>>>(partial, out, nchunk);
}

// Round 16
// 639.848 us; speedup vs baseline: 1.0642x; 1.0642x over previous
//
#include <hip/hip_runtime.h>
#include <math.h>

#define H 128
#define NG 50
#define TB 4096
#define DMAX 12.0f
#define LOG2F_ 0.69314718055994531f

typedef __attribute__((ext_vector_type(8))) short bfrag8;
typedef __attribute__((ext_vector_type(4))) float f32x4;
typedef __attribute__((ext_vector_type(8))) unsigned short u16x8;

__device__ __forceinline__ float sspf(float x) {
    float xc = fminf(x, 60.f);
    float r = __logf(1.f + __expf(xc)) - LOG2F_;
    return r + fmaxf(x - 60.f, 0.f);
}
__device__ __forceinline__ float bf2f(unsigned short u) {
    union { unsigned int i; float f; } c; c.i = ((unsigned int)u) << 16; return c.f;
}
__device__ __forceinline__ unsigned short f2bf(float f) {
    union { float f; unsigned int i; } c; c.f = f;
    unsigned int r = c.i + 0x7fffu + ((c.i >> 16) & 1u);
    return (unsigned short)(r >> 16);
}

// transpose+cast 18 layer weight matrices + readout Ut (blocks 288..319)
__global__ void prep_w_kernel(const float* __restrict__ linW, const float* __restrict__ vW1,
                              const float* __restrict__ vW2, const float* __restrict__ uW1,
                              unsigned short* __restrict__ Wt, unsigned short* __restrict__ Ut) {
    if (blockIdx.x >= 288) {
        int idx = (blockIdx.x - 288) * 256 + threadIdx.x;   // 8192
        int c = idx >> 7, k = idx & 127;
        Ut[c * H + k] = f2bf(uW1[k * 64 + c]);
        return;
    }
    int mat = blockIdx.x >> 4;
    int local = (blockIdx.x & 15) * 256 + threadIdx.x;
    int nrow = local >> 5;
    int k4 = local & 31;
    const float* src = (mat < 6) ? linW + mat * 16384
                     : (mat < 12) ? vW1 + (mat - 6) * 16384
                                  : vW2 + (mat - 12) * 16384;
    ushort4 o;
    o.x = f2bf(src[(k4 * 4 + 0) * H + nrow]);
    o.y = f2bf(src[(k4 * 4 + 1) * H + nrow]);
    o.z = f2bf(src[(k4 * 4 + 2) * H + nrow]);
    o.w = f2bf(src[(k4 * 4 + 3) * H + nrow]);
    *(ushort4*)(Wt + mat * 16384 + nrow * H + k4 * 4) = o;
}

// per-edge distance -> rounded table index; histogram of destination degree
__global__ void edge_dist_kernel(const int* __restrict__ ei, const float* __restrict__ pos,
                                 int* __restrict__ eint, int* __restrict__ deg,
                                 int E_, float inv_step) {
    int e = blockIdx.x * 256 + threadIdx.x;
    if (e >= E_) return;
    int j = ei[e];
    int i = ei[E_ + e];
    float dx = pos[j*3+0] - pos[i*3+0];
    float dy = pos[j*3+1] - pos[i*3+1];
    float dz = pos[j*3+2] - pos[i*3+2];
    float d = sqrtf(dx*dx + dy*dy + dz*dz);
    int ir = (int)(d * inv_step + 0.5f);
    eint[e] = min(ir, TB - 1);
    atomicAdd(&deg[i], 1);
}

// counting-sort phase 1: per-block LDS histogram; LDS-atomic return = local rank.
__global__ void hist_pb_kernel(const int* __restrict__ deg, int* __restrict__ bhist,
                               int* __restrict__ lrank, int n, int nb) {
    __shared__ int h[64];
    const int tid = threadIdx.x;
    if (tid < 64) h[tid] = 0;
    __syncthreads();
    int i = blockIdx.x * 256 + tid;
    if (i < n) lrank[i] = atomicAdd(&h[min(deg[i], 63)], 1);
    __syncthreads();
    if (tid < 64) bhist[tid * nb + blockIdx.x] = h[tid];
}

// counting-sort phase 2: one wave; per-bucket cross-block scan + descending bases
__global__ void scanb_kernel(int* __restrict__ bhist, int* __restrict__ base, int nb) {
    const int b = threadIdx.x;
    int run = 0;
    for (int k0 = 0; k0 < nb; k0 += 8) {
        int v[8];
        #pragma unroll
        for (int u = 0; u < 8; ++u)
            v[u] = (k0 + u < nb) ? bhist[b * nb + k0 + u] : 0;
        #pragma unroll
        for (int u = 0; u < 8; ++u) {
            int t = v[u];
            if (k0 + u < nb) bhist[b * nb + k0 + u] = run;
            run += t;
        }
    }
    int incl = run;
    #pragma unroll
    for (int off = 1; off < 64; off <<= 1) {
        int y = __shfl_up(incl, off, 64);
        if (b >= off) incl += y;
    }
    int total = __shfl(incl, 63, 64);
    base[b] = total - incl;
}

// counting-sort phase 3: pos = base[d] + bofs[blk][d] + lrank[i]. No atomics.
__global__ void place_kernel(const int* __restrict__ deg, const int* __restrict__ bhist,
                             const int* __restrict__ base, const int* __restrict__ lrank,
                             int* __restrict__ perm, int* __restrict__ iperm,
                             int* __restrict__ sdeg, int n, int nb) {
    int i = blockIdx.x * 256 + threadIdx.x;
    if (i >= n) return;
    int d = deg[i];
    int b = min(d, 63);
    int pos = base[b] + bhist[b * nb + blockIdx.x] + lrank[i];
    perm[pos] = i;
    iperm[i] = pos;
    sdeg[pos] = d;
}

// parallel scan phase A: per-block (1024-chunk) sum of sdeg
__global__ void scanA_kernel(const int* __restrict__ sdeg, int* __restrict__ bsum, int n) {
    __shared__ int ws[16];
    int tid = threadIdx.x;
    int idx = blockIdx.x * 1024 + tid;
    int x = (idx < n) ? sdeg[idx] : 0;
    #pragma unroll
    for (int off = 32; off > 0; off >>= 1) x += __shfl_xor(x, off, 64);
    int lane = tid & 63, wid = tid >> 6;
    if (lane == 0) ws[wid] = x;
    __syncthreads();
    if (tid == 0) {
        int s = 0;
        #pragma unroll
        for (int i = 0; i < 16; ++i) s += ws[i];
        bsum[blockIdx.x] = s;
    }
}

// phase C: local scan + self-computed block prefix -> row_ptr, cursor
__global__ void scanC_kernel(const int* __restrict__ sdeg, const int* __restrict__ bsum,
                             int* __restrict__ row_ptr, int* __restrict__ cursor, int n) {
    __shared__ int wsum[16];
    __shared__ int boff_s;
    int tid = threadIdx.x;
    int idx = blockIdx.x * 1024 + tid;
    int lane = tid & 63, wid = tid >> 6;
    if (tid == 0) {
        int s = 0;
        for (int b = 0; b < (int)blockIdx.x; ++b) s += bsum[b];
        boff_s = s;
    }
    int x = (idx < n) ? sdeg[idx] : 0;
    int v = x;
    #pragma unroll
    for (int off = 1; off < 64; off <<= 1) {
        int y = __shfl_up(v, off, 64);
        if (lane >= off) v += y;
    }
    if (lane == 63) wsum[wid] = v;
    __syncthreads();
    int woff = 0;
    for (int w = 0; w < wid; ++w) woff += wsum[w];
    int excl = boff_s + woff + v - x;
    if (idx < n) { row_ptr[idx] = excl; cursor[idx] = excl; }
    if (idx == n - 1) row_ptr[n] = excl + x;
}

// scatter edges into CSR slots (permuted node space), packed (src, tbl-index)
__global__ void csr_fill_kernel(const int* __restrict__ ei, const int* __restrict__ eint,
                                const int* __restrict__ iperm,
                                int* __restrict__ cursor, int2* __restrict__ epack, int E_) {
    int e = blockIdx.x * 256 + threadIdx.x;
    if (e >= E_) return;
    int pi = iperm[ei[E_ + e]];
    int slot = atomicAdd(&cursor[pi], 1);
    epack[slot] = make_int2(iperm[ei[e]], eint[e]);
}

// all 6 layers' filter tables. Block = 32 d-rows of one layer. TB=4096 -> 768 blocks.
__global__ __launch_bounds__(256) void table_all_kernel(
        const float* __restrict__ mW1, const float* __restrict__ mb1,
        const float* __restrict__ mW2, const float* __restrict__ mb2,
        unsigned short* __restrict__ tbl, float step) {
    __shared__ float gs[32][52];
    __shared__ float h1s[32][132];
    const int l = blockIdx.x >> 7;
    const int r0 = (blockIdx.x & 127) * 32;
    const float* W1 = mW1 + l * NG * H;
    const float* b1 = mb1 + l * H;
    const float* W2 = mW2 + l * H * H;
    const float* b2 = mb2 + l * H;
    const int tid = threadIdx.x;
    const float offstep = 10.0f / 49.0f;
    const float coeff = -0.5f / (offstep * offstep);

    for (int idx = tid; idx < 32 * NG; idx += 256) {
        int r = idx / NG, q = idx - r * NG;
        float dd = (r0 + r) * step - q * offstep;
        gs[r][q] = __expf(coeff * dd * dd);
    }
    __syncthreads();

    const int c = tid & 127, rb = (tid >> 7) * 16;
    {
        float acc[16];
        float bv = b1[c];
        #pragma unroll
        for (int r = 0; r < 16; ++r) acc[r] = bv;
        for (int q = 0; q < NG; ++q) {
            float w = W1[q * H + c];
            #pragma unroll
            for (int r = 0; r < 16; ++r) acc[r] = fmaf(gs[rb + r][q], w, acc[r]);
        }
        #pragma unroll
        for (int r = 0; r < 16; ++r) h1s[rb + r][c] = sspf(acc[r]);
    }
    __syncthreads();
    {
        float acc[16];
        float bv = b2[c];
        #pragma unroll
        for (int r = 0; r < 16; ++r) acc[r] = bv;
        for (int f4 = 0; f4 < 32; ++f4) {
            float w0 = W2[(f4 * 4 + 0) * H + c];
            float w1 = W2[(f4 * 4 + 1) * H + c];
            float w2 = W2[(f4 * 4 + 2) * H + c];
            float w3 = W2[(f4 * 4 + 3) * H + c];
            #pragma unroll
            for (int r = 0; r < 16; ++r) {
                float4 h = *(const float4*)&h1s[rb + r][f4 * 4];
                acc[r] = fmaf(h.x, w0, acc[r]);
                acc[r] = fmaf(h.y, w1, acc[r]);
                acc[r] = fmaf(h.z, w2, acc[r]);
                acc[r] = fmaf(h.w, w3, acc[r]);
            }
        }
        #pragma unroll
        for (int r = 0; r < 16; ++r) {
            float d = (r0 + rb + r) * step;
            float C = 0.5f * (cosf(d * 0.31415926535897932f) + 1.0f);
            tbl[(size_t)l * TB * H + (size_t)(r0 + rb + r) * H + c] = f2bf(acc[r] * C);
        }
    }
}

// Fused embed + layer-0 lin GEMM (permuted rows)
__global__ __launch_bounds__(256) void gemm_rs_embed_kernel(
        const int* __restrict__ z, const int* __restrict__ perm,
        const float* __restrict__ emb, const unsigned short* __restrict__ Wt,
        unsigned short* __restrict__ vbf, unsigned short* __restrict__ outB, int n) {
    __shared__ unsigned short t1s[4 * 16 * H];
    const int tid = threadIdx.x;
    const int task = blockIdx.x * 4 + (tid >> 6);
    const int lane = tid & 63, l16 = lane & 15, quad = lane >> 4;
    char* t1w = (char*)(t1s + (tid >> 6) * (16 * H));
    const size_t r0 = (size_t)task * 16;
    const int p = (int)r0 + l16;
    if (p >= n) return;

    const float* erow = emb + (size_t)z[perm[p]] * H;
    bfrag8 af[4];
    #pragma unroll
    for (int kc = 0; kc < 4; ++kc) {
        const int c0 = (kc * 4 + quad) * 8;
        float4 a = *(const float4*)(erow + c0);
        float4 b = *(const float4*)(erow + c0 + 4);
        u16x8 o;
        o[0] = f2bf(a.x); o[1] = f2bf(a.y); o[2] = f2bf(a.z); o[3] = f2bf(a.w);
        o[4] = f2bf(b.x); o[5] = f2bf(b.y); o[6] = f2bf(b.z); o[7] = f2bf(b.w);
        *(u16x8*)(vbf + (size_t)p * H + c0) = o;
        af[kc] = (bfrag8)o;
    }

    #pragma unroll
    for (int ch = 0; ch < 2; ++ch) {
        bfrag8 bf[4][4];
        f32x4 acc[4];
        #pragma unroll
        for (int nt = 0; nt < 4; ++nt) {
            #pragma unroll
            for (int kc = 0; kc < 4; ++kc)
                bf[nt][kc] = *(const bfrag8*)(Wt + (size_t)(ch * 64 + nt * 16 + l16) * H
                                              + (kc * 4 + quad) * 8);
            acc[nt] = (f32x4){0.f, 0.f, 0.f, 0.f};
        }
        #pragma unroll
        for (int nt = 0; nt < 4; ++nt)
            #pragma unroll
            for (int kc = 0; kc < 4; ++kc)
                acc[nt] = __builtin_amdgcn_mfma_f32_16x16x32_bf16(af[kc], bf[nt][kc],
                                                                  acc[nt], 0, 0, 0);
        #pragma unroll
        for (int nt = 0; nt < 4; ++nt) {
            const int col = ch * 64 + nt * 16 + l16;
            const int chunk = col >> 3;
            #pragma unroll
            for (int reg = 0; reg < 4; ++reg) {
                int m = quad * 4 + reg;
                *(unsigned short*)(t1w + m * 256 + ((chunk ^ m) * 16) + (col & 7) * 2)
                    = f2bf(acc[nt][reg]);
            }
        }
    }
    asm volatile("s_waitcnt lgkmcnt(0)" ::: "memory");
    {
        const int m = lane >> 2, cg = lane & 3;
        const size_t gr = r0 + m;
        #pragma unroll
        for (int c4 = 0; c4 < 4; ++c4) {
            int chunk = cg * 4 + c4;
            u16x8 d8 = *(const u16x8*)(t1w + m * 256 + ((chunk ^ m) * 16));
            *(u16x8*)(outB + gr * H + cg * 32 + c4 * 8) = d8;
        }
    }
}

// Merged per-layer kernel (permuted space). W3t==nullptr => fused readout layer.
// launch_bounds (256,8): 8 blocks/CU resident -> 2x gather bytes in flight.
__global__ __launch_bounds__(256, 8) void layer_kernel(
        const int* __restrict__ row_ptr, const int2* __restrict__ epack,
        const unsigned short* __restrict__ tbl, const unsigned short* __restrict__ vlin,
        const unsigned short* __restrict__ W1t, const unsigned short* __restrict__ W2t,
        const unsigned short* __restrict__ W3t,
        const float* __restrict__ b1, const float* __restrict__ b2,
        unsigned short* __restrict__ vbf, unsigned short* __restrict__ outNext,
        const int* __restrict__ batch, const int* __restrict__ perm,
        const unsigned short* __restrict__ Ut, const float* __restrict__ ub1,
        const float* __restrict__ uW2, const float* __restrict__ ub2,
        float* __restrict__ partial, int n) {
    __shared__ unsigned short bufA[16 * H];
    __shared__ unsigned short bufB[16 * H];
    __shared__ float hsum[16];
    __shared__ float gbin[64];
    const int tid = threadIdx.x;
    const int w = tid >> 6, lane = tid & 63;
    const int r0 = blockIdx.x * 16;
    const int l16 = lane & 15, quad = lane >> 4;

    const int rrow = tid >> 4, rcolg = tid & 15;
    const int rnode = r0 + rrow;
    u16x8 rv = {0,0,0,0,0,0,0,0};
    if (rnode < n) rv = *(const u16x8*)(vbf + (size_t)rnode * H + rcolg * 8);

    // ---- phase G: gather (NN table, 4-edge unroll; fits 64-VGPR budget) ----
    {
        const int nd = w * 4 + (lane >> 4);
        const int sub = lane & 15;
        const int node = r0 + nd;
        float acc[8] = {0.f, 0.f, 0.f, 0.f, 0.f, 0.f, 0.f, 0.f};
        if (node < n) {
            const int s = row_ptr[node], e_end = row_ptr[node + 1];
            int k = s;
            for (; k + 4 <= e_end; k += 4) {
                int2 ep[4];
                #pragma unroll
                for (int e = 0; e < 4; ++e) ep[e] = epack[k + e];
                u16x8 wv[4], vj[4];
                #pragma unroll
                for (int e = 0; e < 4; ++e) {
                    wv[e] = *(const u16x8*)(tbl + (size_t)ep[e].y * H + sub * 8);
                    vj[e] = *(const u16x8*)(vlin + (size_t)ep[e].x * H + sub * 8);
                }
                #pragma unroll
                for (int e = 0; e < 4; ++e)
                    #pragma unroll
                    for (int c = 0; c < 8; ++c)
                        acc[c] = fmaf(bf2f(vj[e][c]), bf2f(wv[e][c]), acc[c]);
            }
            for (; k < e_end; ++k) {
                int2 ep = epack[k];
                u16x8 wv = *(const u16x8*)(tbl + (size_t)ep.y * H + sub * 8);
                u16x8 vj = *(const u16x8*)(vlin + (size_t)ep.x * H + sub * 8);
                #pragma unroll
                for (int c = 0; c < 8; ++c)
                    acc[c] = fmaf(bf2f(vj[c]), bf2f(wv[c]), acc[c]);
            }
        }
        u16x8 o;
        #pragma unroll
        for (int c = 0; c < 8; ++c) o[c] = f2bf(acc[c]);
        *(u16x8*)((char*)bufA + nd * 256 + ((sub ^ nd) * 16)) = o;
    }
    __syncthreads();

    // ---- phase 1: t1 cols w*32..+31 ----
    {
        bfrag8 af[4];
        #pragma unroll
        for (int kc = 0; kc < 4; ++kc)
            af[kc] = *(const bfrag8*)((char*)bufA + l16 * 256 + (((kc * 4 + quad) ^ l16) * 16));
        #pragma unroll
        for (int nt2 = 0; nt2 < 2; ++nt2) {
            const int colt = w * 32 + nt2 * 16;
            bfrag8 bf[4];
            #pragma unroll
            for (int kc = 0; kc < 4; ++kc)
                bf[kc] = *(const bfrag8*)(W1t + (size_t)(colt + l16) * H + (kc * 4 + quad) * 8);
            f32x4 acc = (f32x4){0.f, 0.f, 0.f, 0.f};
            #pragma unroll
            for (int kc = 0; kc < 4; ++kc)
                acc = __builtin_amdgcn_mfma_f32_16x16x32_bf16(af[kc], bf[kc], acc, 0, 0, 0);
            const int f = colt + l16;
            const float bv = b1[f];
            const int chunk = f >> 3;
            #pragma unroll
            for (int reg = 0; reg < 4; ++reg) {
                int mr = quad * 4 + reg;
                *(unsigned short*)((char*)bufB + mr * 256 + ((chunk ^ mr) * 16) + (f & 7) * 2)
                    = f2bf(sspf(acc[reg] + bv));
            }
        }
    }
    __syncthreads();

    // ---- phase 2: delta cols w*32..+31 ----
    {
        bfrag8 af[4];
        #pragma unroll
        for (int kc = 0; kc < 4; ++kc)
            af[kc] = *(const bfrag8*)((char*)bufB + l16 * 256 + (((kc * 4 + quad) ^ l16) * 16));
        #pragma unroll
        for (int nt2 = 0; nt2 < 2; ++nt2) {
            const int colt = w * 32 + nt2 * 16;
            bfrag8 bf[4];
            #pragma unroll
            for (int kc = 0; kc < 4; ++kc)
                bf[kc] = *(const bfrag8*)(W2t + (size_t)(colt + l16) * H + (kc * 4 + quad) * 8);
            f32x4 acc = (f32x4){0.f, 0.f, 0.f, 0.f};
            #pragma unroll
            for (int kc = 0; kc < 4; ++kc)
                acc = __builtin_amdgcn_mfma_f32_16x16x32_bf16(af[kc], bf[kc], acc, 0, 0, 0);
            const int col = colt + l16;
            const float bv = b2[col];
            const int chunk = col >> 3;
            #pragma unroll
            for (int reg = 0; reg < 4; ++reg) {
                int mr = quad * 4 + reg;
                *(unsigned short*)((char*)bufA + mr * 256 + ((chunk ^ mr) * 16) + (col & 7) * 2)
                    = f2bf(acc[reg] + bv);
            }
        }
    }
    __syncthreads();

    // ---- phase R: vnew = rv + delta -> vbf, stash -> bufB; zero readout bins ----
    {
        u16x8 d8 = *(const u16x8*)((char*)bufA + rrow * 256 + ((rcolg ^ rrow) * 16));
        u16x8 ob;
        #pragma unroll
        for (int c = 0; c < 8; ++c) ob[c] = f2bf(bf2f(rv[c]) + bf2f(d8[c]));
        if (rnode < n) *(u16x8*)(vbf + (size_t)rnode * H + rcolg * 8) = ob;
        *(u16x8*)((char*)bufB + rrow * 256 + ((rcolg ^ rrow) * 16)) = ob;
        if (tid < 16) hsum[tid] = 0.f;
        if (tid < 64) gbin[tid] = 0.f;
    }
    __syncthreads();

    if (W3t) {
        // ---- phase 3: vlin_next cols w*32..+31 ----
        bfrag8 af[4];
        #pragma unroll
        for (int kc = 0; kc < 4; ++kc)
            af[kc] = *(const bfrag8*)((char*)bufB + l16 * 256 + (((kc * 4 + quad) ^ l16) * 16));
        #pragma unroll
        for (int nt2 = 0; nt2 < 2; ++nt2) {
            const int colt = w * 32 + nt2 * 16;
            bfrag8 bf[4];
            #pragma unroll
            for (int kc = 0; kc < 4; ++kc)
                bf[kc] = *(const bfrag8*)(W3t + (size_t)(colt + l16) * H + (kc * 4 + quad) * 8);
            f32x4 acc = (f32x4){0.f, 0.f, 0.f, 0.f};
            #pragma unroll
            for (int kc = 0; kc < 4; ++kc)
                acc = __builtin_amdgcn_mfma_f32_16x16x32_bf16(af[kc], bf[kc], acc, 0, 0, 0);
            const int col = colt + l16;
            const int chunk = col >> 3;
            #pragma unroll
            for (int reg = 0; reg < 4; ++reg) {
                int mr = quad * 4 + reg;
                *(unsigned short*)((char*)bufA + mr * 256 + ((chunk ^ mr) * 16) + (col & 7) * 2)
                    = f2bf(acc[reg]);
            }
        }
        __syncthreads();
        u16x8 d8 = *(const u16x8*)((char*)bufA + rrow * 256 + ((rcolg ^ rrow) * 16));
        if (rnode < n) *(u16x8*)(outNext + (size_t)rnode * H + rcolg * 8) = d8;
    } else {
        // ---- fused readout: h = ssp(vnew@Ut^T + ub1)·uW2, binned per graph ----
        bfrag8 af[4];
        #pragma unroll
        for (int kc = 0; kc < 4; ++kc)
            af[kc] = *(const bfrag8*)((char*)bufB + l16 * 256 + (((kc * 4 + quad) ^ l16) * 16));
        const int colu = w * 16 + l16;
        bfrag8 bfu[4];
        #pragma unroll
        for (int kc = 0; kc < 4; ++kc)
            bfu[kc] = *(const bfrag8*)(Ut + (size_t)colu * H + (kc * 4 + quad) * 8);
        f32x4 acc = (f32x4){0.f, 0.f, 0.f, 0.f};
        #pragma unroll
        for (int kc = 0; kc < 4; ++kc)
            acc = __builtin_amdgcn_mfma_f32_16x16x32_bf16(af[kc], bfu[kc], acc, 0, 0, 0);
        const float b1v = ub1[colu], w2v = uW2[colu];
        #pragma unroll
        for (int reg = 0; reg < 4; ++reg) {
            float s = sspf(acc[reg] + b1v) * w2v;
            s += __shfl_xor(s, 1, 64);
            s += __shfl_xor(s, 2, 64);
            s += __shfl_xor(s, 4, 64);
            s += __shfl_xor(s, 8, 64);
            if (l16 == 0) atomicAdd(&hsum[quad * 4 + reg], s);
        }
        __syncthreads();
        if (tid < 16) {
            int node = r0 + tid;
            if (node < n) atomicAdd(&gbin[batch[perm[node]]], hsum[tid] + ub2[0]);
        }
        __syncthreads();
        if (tid < 64) partial[(size_t)blockIdx.x * 64 + tid] = gbin[tid];
    }
}

// readout stage 2: out[g] = sum over nchunk blocks of partial[b][g]
__global__ void readout2_kernel(const float* __restrict__ partial, float* __restrict__ out,
                                int nb) {
    __shared__ float red[1024];
    const int tid = threadIdx.x;
    const int g = tid & 63, q = tid >> 6;
    float acc = 0.f;
    for (int b = q; b < nb; b += 16) acc += partial[(size_t)b * 64 + g];
    red[tid] = acc;
    __syncthreads();
    if (tid < 64) {
        float s = 0.f;
        #pragma unroll
        for (int k = 0; k < 16; ++k) s += red[k * 64 + tid];
        out[tid] = s;
    }
}

extern "C" void kernel_launch(void* const* d_in, const int* in_sizes, int n_in,
                              void* d_out, int out_size, void* d_ws, size_t ws_size,
                              hipStream_t stream) {
    const int*   z       = (const int*)d_in[0];
    const float* pos     = (const float*)d_in[1];
    const int*   batch   = (const int*)d_in[2];
    const int*   ei      = (const int*)d_in[3];
    const float* emb     = (const float*)d_in[4];
    const float* lin_W   = (const float*)d_in[5];
    const float* mlp_W1  = (const float*)d_in[6];
    const float* mlp_b1  = (const float*)d_in[7];
    const float* mlp_W2  = (const float*)d_in[8];
    const float* mlp_b2  = (const float*)d_in[9];
    const float* v_W1    = (const float*)d_in[10];
    const float* v_b1    = (const float*)d_in[11];
    const float* v_W2    = (const float*)d_in[12];
    const float* v_b2    = (const float*)d_in[13];
    const float* u_W1    = (const float*)d_in[14];
    const float* u_b1    = (const float*)d_in[15];
    const float* u_W2    = (const float*)d_in[16];
    const float* u_b2    = (const float*)d_in[17];
    const int n  = in_sizes[0];
    const int E_ = in_sizes[3] / 2;
    float* out = (float*)d_out;

    char* wp = (char*)d_ws;
    auto alloc = [&](size_t bytes) { char* p = wp; wp += (bytes + 255) & ~(size_t)255; return p; };
    const int NB1K = (n + 1023) / 1024;
    const int NB256 = (n + 255) / 256;
    const int nchunk = (n + 15) / 16;
    unsigned short* vbf     = (unsigned short*)alloc((size_t)n * H * 2);
    unsigned short* vlinA   = (unsigned short*)alloc((size_t)n * H * 2);
    unsigned short* vlinB   = (unsigned short*)alloc((size_t)n * H * 2);
    unsigned short* WtAll   = (unsigned short*)alloc((size_t)18 * H * H * 2);
    unsigned short* Ut      = (unsigned short*)alloc((size_t)64 * H * 2);
    unsigned short* tbl     = (unsigned short*)alloc((size_t)6 * TB * H * 2);
    int*   eint    = (int*)alloc((size_t)E_ * 4);
    int2*  epack   = (int2*)alloc((size_t)E_ * 8);
    int*   deg     = (int*)alloc((size_t)n * 4);
    int*   sdeg    = (int*)alloc((size_t)n * 4);
    int*   perm    = (int*)alloc((size_t)n * 4);
    int*   iperm   = (int*)alloc((size_t)n * 4);
    int*   lrank   = (int*)alloc((size_t)n * 4);
    int*   row_ptr = (int*)alloc((size_t)(n + 1) * 4);
    int*   cursor  = (int*)alloc((size_t)n * 4);
    int*   bsum    = (int*)alloc((size_t)NB1K * 4);
    int*   bhist   = (int*)alloc((size_t)64 * NB256 * 4);
    int*   base    = (int*)alloc(64 * 4);
    float* partial = (float*)alloc((size_t)nchunk * 64 * 4);

    const float step = DMAX / TB;
    hipMemsetAsync(deg, 0, (size_t)n * 4, stream);

    prep_w_kernel<<<320, 256, 0, stream>>>(lin_W, v_W1, v_W2, u_W1, WtAll, Ut);
    table_all_kernel<<<768, 256, 0, stream>>>(mlp_W1, mlp_b1, mlp_W2, mlp_b2, tbl, step);
    edge_dist_kernel<<<(E_ + 255) / 256, 256, 0, stream>>>(ei, pos, eint, deg, E_, 1.0f / step);
    hist_pb_kernel<<<NB256, 256, 0, stream>>>(deg, bhist, lrank, n, NB256);
    scanb_kernel<<<1, 64, 0, stream>>>(bhist, base, NB256);
    place_kernel<<<NB256, 256, 0, stream>>>(deg, bhist, base, lrank, perm, iperm, sdeg, n, NB256);
    scanA_kernel<<<NB1K, 1024, 0, stream>>>(sdeg, bsum, n);
    scanC_kernel<<<NB1K, 1024, 0, stream>>>(sdeg, bsum, row_ptr, cursor, n);
    csr_fill_kernel<<<(E_ + 255) / 256, 256, 0, stream>>>(ei, eint, iperm, cursor, epack, E_);

    const int GRS = (nchunk + 3) / 4;
    gemm_rs_embed_kernel<<<GRS, 256, 0, stream>>>(z, perm, emb, WtAll, vbf, vlinA, n);
    unsigned short* cur = vlinA;
    unsigned short* nxt = vlinB;
    for (int l = 0; l < 6; ++l) {
        const unsigned short* W3t = (l < 5) ? (WtAll + (l + 1) * H * H) : nullptr;
        layer_kernel<<<nchunk, 256, 0, stream>>>(row_ptr, epack,
                                                 tbl + (size_t)l * TB * H, cur,
                                                 WtAll + (6 + l) * H * H,
                                                 WtAll + (12 + l) * H * H, W3t,
                                                 v_b1 + l * H, v_b2 + l * H,
                                                 vbf, nxt,
                                                 batch, perm, Ut, u_b1, u_W2, u_b2,
                                                 partial, n);
        unsigned short* tmp = cur; cur = nxt; nxt = tmp;
    }
    readout2_kernel<<<1, 1024, 0, stream>>>(partial, out, nchunk);
}

// Round 17
// 633.253 us; speedup vs baseline: 1.0752x; 1.0104x over previous
//
#include <hip/hip_runtime.h>
#include <math.h>

#define H 128
#define NG 50
#define TB 2048
#define DMAX 12.0f
#define LOG2F_ 0.69314718055994531f

typedef __attribute__((ext_vector_type(8))) short bfrag8;
typedef __attribute__((ext_vector_type(4))) float f32x4;
typedef __attribute__((ext_vector_type(8))) unsigned short u16x8;

__device__ __forceinline__ float sspf(float x) {
    float xc = fminf(x, 60.f);
    float r = __logf(1.f + __expf(xc)) - LOG2F_;
    return r + fmaxf(x - 60.f, 0.f);
}
__device__ __forceinline__ float bf2f(unsigned short u) {
    union { unsigned int i; float f; } c; c.i = ((unsigned int)u) << 16; return c.f;
}
__device__ __forceinline__ unsigned short f2bf(float f) {
    union { float f; unsigned int i; } c; c.f = f;
    unsigned int r = c.i + 0x7fffu + ((c.i >> 16) & 1u);
    return (unsigned short)(r >> 16);
}

// transpose+cast 18 layer weight matrices + readout Ut (blocks 288..319)
__global__ void prep_w_kernel(const float* __restrict__ linW, const float* __restrict__ vW1,
                              const float* __restrict__ vW2, const float* __restrict__ uW1,
                              unsigned short* __restrict__ Wt, unsigned short* __restrict__ Ut) {
    if (blockIdx.x >= 288) {
        int idx = (blockIdx.x - 288) * 256 + threadIdx.x;   // 8192
        int c = idx >> 7, k = idx & 127;
        Ut[c * H + k] = f2bf(uW1[k * 64 + c]);
        return;
    }
    int mat = blockIdx.x >> 4;
    int local = (blockIdx.x & 15) * 256 + threadIdx.x;
    int nrow = local >> 5;
    int k4 = local & 31;
    const float* src = (mat < 6) ? linW + mat * 16384
                     : (mat < 12) ? vW1 + (mat - 6) * 16384
                                  : vW2 + (mat - 12) * 16384;
    ushort4 o;
    o.x = f2bf(src[(k4 * 4 + 0) * H + nrow]);
    o.y = f2bf(src[(k4 * 4 + 1) * H + nrow]);
    o.z = f2bf(src[(k4 * 4 + 2) * H + nrow]);
    o.w = f2bf(src[(k4 * 4 + 3) * H + nrow]);
    *(ushort4*)(Wt + mat * 16384 + nrow * H + k4 * 4) = o;
}

// per-edge distance -> rounded table index; histogram of destination degree
__global__ void edge_dist_kernel(const int* __restrict__ ei, const float* __restrict__ pos,
                                 int* __restrict__ eint, int* __restrict__ deg,
                                 int E_, float inv_step) {
    int e = blockIdx.x * 256 + threadIdx.x;
    if (e >= E_) return;
    int j = ei[e];
    int i = ei[E_ + e];
    float dx = pos[j*3+0] - pos[i*3+0];
    float dy = pos[j*3+1] - pos[i*3+1];
    float dz = pos[j*3+2] - pos[i*3+2];
    float d = sqrtf(dx*dx + dy*dy + dz*dz);
    int ir = (int)(d * inv_step + 0.5f);
    eint[e] = min(ir, TB - 1);
    atomicAdd(&deg[i], 1);
}

// counting-sort phase 1: per-block LDS histogram; LDS-atomic return = local rank.
__global__ void hist_pb_kernel(const int* __restrict__ deg, int* __restrict__ bhist,
                               int* __restrict__ lrank, int n, int nb) {
    __shared__ int h[64];
    const int tid = threadIdx.x;
    if (tid < 64) h[tid] = 0;
    __syncthreads();
    int i = blockIdx.x * 256 + tid;
    if (i < n) lrank[i] = atomicAdd(&h[min(deg[i], 63)], 1);
    __syncthreads();
    if (tid < 64) bhist[tid * nb + blockIdx.x] = h[tid];
}

// counting-sort phase 2: one wave; per-bucket cross-block scan + descending bases
__global__ void scanb_kernel(int* __restrict__ bhist, int* __restrict__ base, int nb) {
    const int b = threadIdx.x;
    int run = 0;
    for (int k0 = 0; k0 < nb; k0 += 8) {
        int v[8];
        #pragma unroll
        for (int u = 0; u < 8; ++u)
            v[u] = (k0 + u < nb) ? bhist[b * nb + k0 + u] : 0;
        #pragma unroll
        for (int u = 0; u < 8; ++u) {
            int t = v[u];
            if (k0 + u < nb) bhist[b * nb + k0 + u] = run;
            run += t;
        }
    }
    int incl = run;
    #pragma unroll
    for (int off = 1; off < 64; off <<= 1) {
        int y = __shfl_up(incl, off, 64);
        if (b >= off) incl += y;
    }
    int total = __shfl(incl, 63, 64);
    base[b] = total - incl;
}

// counting-sort phase 3: pos = base[d] + bofs[blk][d] + lrank[i]. No atomics.
__global__ void place_kernel(const int* __restrict__ deg, const int* __restrict__ bhist,
                             const int* __restrict__ base, const int* __restrict__ lrank,
                             int* __restrict__ perm, int* __restrict__ iperm,
                             int* __restrict__ sdeg, int n, int nb) {
    int i = blockIdx.x * 256 + threadIdx.x;
    if (i >= n) return;
    int d = deg[i];
    int b = min(d, 63);
    int pos = base[b] + bhist[b * nb + blockIdx.x] + lrank[i];
    perm[pos] = i;
    iperm[i] = pos;
    sdeg[pos] = d;
}

// parallel scan phase A: per-block (1024-chunk) sum of sdeg
__global__ void scanA_kernel(const int* __restrict__ sdeg, int* __restrict__ bsum, int n) {
    __shared__ int ws[16];
    int tid = threadIdx.x;
    int idx = blockIdx.x * 1024 + tid;
    int x = (idx < n) ? sdeg[idx] : 0;
    #pragma unroll
    for (int off = 32; off > 0; off >>= 1) x += __shfl_xor(x, off, 64);
    int lane = tid & 63, wid = tid >> 6;
    if (lane == 0) ws[wid] = x;
    __syncthreads();
    if (tid == 0) {
        int s = 0;
        #pragma unroll
        for (int i = 0; i < 16; ++i) s += ws[i];
        bsum[blockIdx.x] = s;
    }
}

// phase C: local scan + self-computed block prefix -> row_ptr, cursor
__global__ void scanC_kernel(const int* __restrict__ sdeg, const int* __restrict__ bsum,
                             int* __restrict__ row_ptr, int* __restrict__ cursor, int n) {
    __shared__ int wsum[16];
    __shared__ int boff_s;
    int tid = threadIdx.x;
    int idx = blockIdx.x * 1024 + tid;
    int lane = tid & 63, wid = tid >> 6;
    if (tid == 0) {
        int s = 0;
        for (int b = 0; b < (int)blockIdx.x; ++b) s += bsum[b];
        boff_s = s;
    }
    int x = (idx < n) ? sdeg[idx] : 0;
    int v = x;
    #pragma unroll
    for (int off = 1; off < 64; off <<= 1) {
        int y = __shfl_up(v, off, 64);
        if (lane >= off) v += y;
    }
    if (lane == 63) wsum[wid] = v;
    __syncthreads();
    int woff = 0;
    for (int w = 0; w < wid; ++w) woff += wsum[w];
    int excl = boff_s + woff + v - x;
    if (idx < n) { row_ptr[idx] = excl; cursor[idx] = excl; }
    if (idx == n - 1) row_ptr[n] = excl + x;
}

// scatter edges into CSR slots (permuted node space), packed (src, tbl-index)
__global__ void csr_fill_kernel(const int* __restrict__ ei, const int* __restrict__ eint,
                                const int* __restrict__ iperm,
                                int* __restrict__ cursor, int2* __restrict__ epack, int E_) {
    int e = blockIdx.x * 256 + threadIdx.x;
    if (e >= E_) return;
    int pi = iperm[ei[E_ + e]];
    int slot = atomicAdd(&cursor[pi], 1);
    epack[slot] = make_int2(iperm[ei[e]], eint[e]);
}

// all 6 layers' filter tables. Block = 32 d-rows of one layer. TB=2048 -> 384 blocks.
__global__ __launch_bounds__(256) void table_all_kernel(
        const float* __restrict__ mW1, const float* __restrict__ mb1,
        const float* __restrict__ mW2, const float* __restrict__ mb2,
        unsigned short* __restrict__ tbl, float step) {
    __shared__ float gs[32][52];
    __shared__ float h1s[32][132];
    const int l = blockIdx.x >> 6;
    const int r0 = (blockIdx.x & 63) * 32;
    const float* W1 = mW1 + l * NG * H;
    const float* b1 = mb1 + l * H;
    const float* W2 = mW2 + l * H * H;
    const float* b2 = mb2 + l * H;
    const int tid = threadIdx.x;
    const float offstep = 10.0f / 49.0f;
    const float coeff = -0.5f / (offstep * offstep);

    for (int idx = tid; idx < 32 * NG; idx += 256) {
        int r = idx / NG, q = idx - r * NG;
        float dd = (r0 + r) * step - q * offstep;
        gs[r][q] = __expf(coeff * dd * dd);
    }
    __syncthreads();

    const int c = tid & 127, rb = (tid >> 7) * 16;
    {
        float acc[16];
        float bv = b1[c];
        #pragma unroll
        for (int r = 0; r < 16; ++r) acc[r] = bv;
        for (int q = 0; q < NG; ++q) {
            float w = W1[q * H + c];
            #pragma unroll
            for (int r = 0; r < 16; ++r) acc[r] = fmaf(gs[rb + r][q], w, acc[r]);
        }
        #pragma unroll
        for (int r = 0; r < 16; ++r) h1s[rb + r][c] = sspf(acc[r]);
    }
    __syncthreads();
    {
        float acc[16];
        float bv = b2[c];
        #pragma unroll
        for (int r = 0; r < 16; ++r) acc[r] = bv;
        for (int f4 = 0; f4 < 32; ++f4) {
            float w0 = W2[(f4 * 4 + 0) * H + c];
            float w1 = W2[(f4 * 4 + 1) * H + c];
            float w2 = W2[(f4 * 4 + 2) * H + c];
            float w3 = W2[(f4 * 4 + 3) * H + c];
            #pragma unroll
            for (int r = 0; r < 16; ++r) {
                float4 h = *(const float4*)&h1s[rb + r][f4 * 4];
                acc[r] = fmaf(h.x, w0, acc[r]);
                acc[r] = fmaf(h.y, w1, acc[r]);
                acc[r] = fmaf(h.z, w2, acc[r]);
                acc[r] = fmaf(h.w, w3, acc[r]);
            }
        }
        #pragma unroll
        for (int r = 0; r < 16; ++r) {
            float d = (r0 + rb + r) * step;
            float C = 0.5f * (cosf(d * 0.31415926535897932f) + 1.0f);
            tbl[(size_t)l * TB * H + (size_t)(r0 + rb + r) * H + c] = f2bf(acc[r] * C);
        }
    }
}

// Fused embed + layer-0 lin GEMM (permuted rows)
__global__ __launch_bounds__(256) void gemm_rs_embed_kernel(
        const int* __restrict__ z, const int* __restrict__ perm,
        const float* __restrict__ emb, const unsigned short* __restrict__ Wt,
        unsigned short* __restrict__ vbf, unsigned short* __restrict__ outB, int n) {
    __shared__ unsigned short t1s[4 * 16 * H];
    const int tid = threadIdx.x;
    const int task = blockIdx.x * 4 + (tid >> 6);
    const int lane = tid & 63, l16 = lane & 15, quad = lane >> 4;
    char* t1w = (char*)(t1s + (tid >> 6) * (16 * H));
    const size_t r0 = (size_t)task * 16;
    const int p = (int)r0 + l16;
    if (p >= n) return;

    const float* erow = emb + (size_t)z[perm[p]] * H;
    bfrag8 af[4];
    #pragma unroll
    for (int kc = 0; kc < 4; ++kc) {
        const int c0 = (kc * 4 + quad) * 8;
        float4 a = *(const float4*)(erow + c0);
        float4 b = *(const float4*)(erow + c0 + 4);
        u16x8 o;
        o[0] = f2bf(a.x); o[1] = f2bf(a.y); o[2] = f2bf(a.z); o[3] = f2bf(a.w);
        o[4] = f2bf(b.x); o[5] = f2bf(b.y); o[6] = f2bf(b.z); o[7] = f2bf(b.w);
        *(u16x8*)(vbf + (size_t)p * H + c0) = o;
        af[kc] = (bfrag8)o;
    }

    #pragma unroll
    for (int ch = 0; ch < 2; ++ch) {
        bfrag8 bf[4][4];
        f32x4 acc[4];
        #pragma unroll
        for (int nt = 0; nt < 4; ++nt) {
            #pragma unroll
            for (int kc = 0; kc < 4; ++kc)
                bf[nt][kc] = *(const bfrag8*)(Wt + (size_t)(ch * 64 + nt * 16 + l16) * H
                                              + (kc * 4 + quad) * 8);
            acc[nt] = (f32x4){0.f, 0.f, 0.f, 0.f};
        }
        #pragma unroll
        for (int nt = 0; nt < 4; ++nt)
            #pragma unroll
            for (int kc = 0; kc < 4; ++kc)
                acc[nt] = __builtin_amdgcn_mfma_f32_16x16x32_bf16(af[kc], bf[nt][kc],
                                                                  acc[nt], 0, 0, 0);
        #pragma unroll
        for (int nt = 0; nt < 4; ++nt) {
            const int col = ch * 64 + nt * 16 + l16;
            const int chunk = col >> 3;
            #pragma unroll
            for (int reg = 0; reg < 4; ++reg) {
                int m = quad * 4 + reg;
                *(unsigned short*)(t1w + m * 256 + ((chunk ^ m) * 16) + (col & 7) * 2)
                    = f2bf(acc[nt][reg]);
            }
        }
    }
    asm volatile("s_waitcnt lgkmcnt(0)" ::: "memory");
    {
        const int m = lane >> 2, cg = lane & 3;
        const size_t gr = r0 + m;
        #pragma unroll
        for (int c4 = 0; c4 < 4; ++c4) {
            int chunk = cg * 4 + c4;
            u16x8 d8 = *(const u16x8*)(t1w + m * 256 + ((chunk ^ m) * 16));
            *(u16x8*)(outB + gr * H + cg * 32 + c4 * 8) = d8;
        }
    }
}

// Merged per-layer kernel. (256,6): ~84 VGPR cap, 6 blocks/CU — no spill.
__global__ __launch_bounds__(256, 6) void layer_kernel(
        const int* __restrict__ row_ptr, const int2* __restrict__ epack,
        const unsigned short* __restrict__ tbl, const unsigned short* __restrict__ vlin,
        const unsigned short* __restrict__ W1t, const unsigned short* __restrict__ W2t,
        const unsigned short* __restrict__ W3t,
        const float* __restrict__ b1, const float* __restrict__ b2,
        unsigned short* __restrict__ vbf, unsigned short* __restrict__ outNext,
        const int* __restrict__ batch, const int* __restrict__ perm,
        const unsigned short* __restrict__ Ut, const float* __restrict__ ub1,
        const float* __restrict__ uW2, const float* __restrict__ ub2,
        float* __restrict__ partial, int n) {
    __shared__ unsigned short bufA[16 * H];
    __shared__ unsigned short bufB[16 * H];
    __shared__ float hsum[16];
    __shared__ float gbin[64];
    const int tid = threadIdx.x;
    const int w = tid >> 6, lane = tid & 63;
    const int r0 = blockIdx.x * 16;
    const int l16 = lane & 15, quad = lane >> 4;
    const int rrow = tid >> 4, rcolg = tid & 15;
    const int rnode = r0 + rrow;

    // ---- phase G: gather (NN table, 4-edge unroll) ----
    {
        const int nd = w * 4 + (lane >> 4);
        const int sub = lane & 15;
        const int node = r0 + nd;
        float acc[8] = {0.f, 0.f, 0.f, 0.f, 0.f, 0.f, 0.f, 0.f};
        if (node < n) {
            const int s = row_ptr[node], e_end = row_ptr[node + 1];
            int k = s;
            for (; k + 4 <= e_end; k += 4) {
                int2 ep[4];
                #pragma unroll
                for (int e = 0; e < 4; ++e) ep[e] = epack[k + e];
                u16x8 wv[4], vj[4];
                #pragma unroll
                for (int e = 0; e < 4; ++e) {
                    wv[e] = *(const u16x8*)(tbl + (size_t)ep[e].y * H + sub * 8);
                    vj[e] = *(const u16x8*)(vlin + (size_t)ep[e].x * H + sub * 8);
                }
                #pragma unroll
                for (int e = 0; e < 4; ++e)
                    #pragma unroll
                    for (int c = 0; c < 8; ++c)
                        acc[c] = fmaf(bf2f(vj[e][c]), bf2f(wv[e][c]), acc[c]);
            }
            for (; k < e_end; ++k) {
                int2 ep = epack[k];
                u16x8 wv = *(const u16x8*)(tbl + (size_t)ep.y * H + sub * 8);
                u16x8 vj = *(const u16x8*)(vlin + (size_t)ep.x * H + sub * 8);
                #pragma unroll
                for (int c = 0; c < 8; ++c)
                    acc[c] = fmaf(bf2f(vj[c]), bf2f(wv[c]), acc[c]);
            }
        }
        u16x8 o;
        #pragma unroll
        for (int c = 0; c < 8; ++c) o[c] = f2bf(acc[c]);
        *(u16x8*)((char*)bufA + nd * 256 + ((sub ^ nd) * 16)) = o;
    }
    __syncthreads();

    // ---- phase 1: t1 cols w*32..+31 ----
    {
        bfrag8 af[4];
        #pragma unroll
        for (int kc = 0; kc < 4; ++kc)
            af[kc] = *(const bfrag8*)((char*)bufA + l16 * 256 + (((kc * 4 + quad) ^ l16) * 16));
        #pragma unroll
        for (int nt2 = 0; nt2 < 2; ++nt2) {
            const int colt = w * 32 + nt2 * 16;
            bfrag8 bf[4];
            #pragma unroll
            for (int kc = 0; kc < 4; ++kc)
                bf[kc] = *(const bfrag8*)(W1t + (size_t)(colt + l16) * H + (kc * 4 + quad) * 8);
            f32x4 acc = (f32x4){0.f, 0.f, 0.f, 0.f};
            #pragma unroll
            for (int kc = 0; kc < 4; ++kc)
                acc = __builtin_amdgcn_mfma_f32_16x16x32_bf16(af[kc], bf[kc], acc, 0, 0, 0);
            const int f = colt + l16;
            const float bv = b1[f];
            const int chunk = f >> 3;
            #pragma unroll
            for (int reg = 0; reg < 4; ++reg) {
                int mr = quad * 4 + reg;
                *(unsigned short*)((char*)bufB + mr * 256 + ((chunk ^ mr) * 16) + (f & 7) * 2)
                    = f2bf(sspf(acc[reg] + bv));
            }
        }
    }
    __syncthreads();

    // ---- phase 2: delta cols w*32..+31 ----
    {
        bfrag8 af[4];
        #pragma unroll
        for (int kc = 0; kc < 4; ++kc)
            af[kc] = *(const bfrag8*)((char*)bufB + l16 * 256 + (((kc * 4 + quad) ^ l16) * 16));
        #pragma unroll
        for (int nt2 = 0; nt2 < 2; ++nt2) {
            const int colt = w * 32 + nt2 * 16;
            bfrag8 bf[4];
            #pragma unroll
            for (int kc = 0; kc < 4; ++kc)
                bf[kc] = *(const bfrag8*)(W2t + (size_t)(colt + l16) * H + (kc * 4 + quad) * 8);
            f32x4 acc = (f32x4){0.f, 0.f, 0.f, 0.f};
            #pragma unroll
            for (int kc = 0; kc < 4; ++kc)
                acc = __builtin_amdgcn_mfma_f32_16x16x32_bf16(af[kc], bf[kc], acc, 0, 0, 0);
            const int col = colt + l16;
            const float bv = b2[col];
            const int chunk = col >> 3;
            #pragma unroll
            for (int reg = 0; reg < 4; ++reg) {
                int mr = quad * 4 + reg;
                *(unsigned short*)((char*)bufA + mr * 256 + ((chunk ^ mr) * 16) + (col & 7) * 2)
                    = f2bf(acc[reg] + bv);
            }
        }
    }
    __syncthreads();

    // ---- phase R: vnew = vbf + delta -> vbf, stash -> bufB (rv loaded here) ----
    {
        u16x8 rv = {0,0,0,0,0,0,0,0};
        if (rnode < n) rv = *(const u16x8*)(vbf + (size_t)rnode * H + rcolg * 8);
        u16x8 d8 = *(const u16x8*)((char*)bufA + rrow * 256 + ((rcolg ^ rrow) * 16));
        u16x8 ob;
        #pragma unroll
        for (int c = 0; c < 8; ++c) ob[c] = f2bf(bf2f(rv[c]) + bf2f(d8[c]));
        if (rnode < n) *(u16x8*)(vbf + (size_t)rnode * H + rcolg * 8) = ob;
        *(u16x8*)((char*)bufB + rrow * 256 + ((rcolg ^ rrow) * 16)) = ob;
        if (tid < 16) hsum[tid] = 0.f;
        if (tid < 64) gbin[tid] = 0.f;
    }
    __syncthreads();

    if (W3t) {
        // ---- phase 3: vlin_next cols w*32..+31 ----
        bfrag8 af[4];
        #pragma unroll
        for (int kc = 0; kc < 4; ++kc)
            af[kc] = *(const bfrag8*)((char*)bufB + l16 * 256 + (((kc * 4 + quad) ^ l16) * 16));
        #pragma unroll
        for (int nt2 = 0; nt2 < 2; ++nt2) {
            const int colt = w * 32 + nt2 * 16;
            bfrag8 bf[4];
            #pragma unroll
            for (int kc = 0; kc < 4; ++kc)
                bf[kc] = *(const bfrag8*)(W3t + (size_t)(colt + l16) * H + (kc * 4 + quad) * 8);
            f32x4 acc = (f32x4){0.f, 0.f, 0.f, 0.f};
            #pragma unroll
            for (int kc = 0; kc < 4; ++kc)
                acc = __builtin_amdgcn_mfma_f32_16x16x32_bf16(af[kc], bf[kc], acc, 0, 0, 0);
            const int col = colt + l16;
            const int chunk = col >> 3;
            #pragma unroll
            for (int reg = 0; reg < 4; ++reg) {
                int mr = quad * 4 + reg;
                *(unsigned short*)((char*)bufA + mr * 256 + ((chunk ^ mr) * 16) + (col & 7) * 2)
                    = f2bf(acc[reg]);
            }
        }
        __syncthreads();
        u16x8 d8 = *(const u16x8*)((char*)bufA + rrow * 256 + ((rcolg ^ rrow) * 16));
        if (rnode < n) *(u16x8*)(outNext + (size_t)rnode * H + rcolg * 8) = d8;
    } else {
        // ---- fused readout: h = ssp(vnew@Ut^T + ub1)·uW2, binned per graph ----
        bfrag8 af[4];
        #pragma unroll
        for (int kc = 0; kc < 4; ++kc)
            af[kc] = *(const bfrag8*)((char*)bufB + l16 * 256 + (((kc * 4 + quad) ^ l16) * 16));
        const int colu = w * 16 + l16;
        bfrag8 bfu[4];
        #pragma unroll
        for (int kc = 0; kc < 4; ++kc)
            bfu[kc] = *(const bfrag8*)(Ut + (size_t)colu * H + (kc * 4 + quad) * 8);
        f32x4 acc = (f32x4){0.f, 0.f, 0.f, 0.f};
        #pragma unroll
        for (int kc = 0; kc < 4; ++kc)
            acc = __builtin_amdgcn_mfma_f32_16x16x32_bf16(af[kc], bfu[kc], acc, 0, 0, 0);
        const float b1v = ub1[colu], w2v = uW2[colu];
        #pragma unroll
        for (int reg = 0; reg < 4; ++reg) {
            float s = sspf(acc[reg] + b1v) * w2v;
            s += __shfl_xor(s, 1, 64);
            s += __shfl_xor(s, 2, 64);
            s += __shfl_xor(s, 4, 64);
            s += __shfl_xor(s, 8, 64);
            if (l16 == 0) atomicAdd(&hsum[quad * 4 + reg], s);
        }
        __syncthreads();
        if (tid < 16) {
            int node = r0 + tid;
            if (node < n) atomicAdd(&gbin[batch[perm[node]]], hsum[tid] + ub2[0]);
        }
        __syncthreads();
        if (tid < 64) partial[(size_t)blockIdx.x * 64 + tid] = gbin[tid];
    }
}

// readout stage 2: out[g] = sum over nchunk blocks of partial[b][g]
__global__ void readout2_kernel(const float* __restrict__ partial, float* __restrict__ out,
                                int nb) {
    __shared__ float red[1024];
    const int tid = threadIdx.x;
    const int g = tid & 63, q = tid >> 6;
    float acc = 0.f;
    for (int b = q; b < nb; b += 16) acc += partial[(size_t)b * 64 + g];
    red[tid] = acc;
    __syncthreads();
    if (tid < 64) {
        float s = 0.f;
        #pragma unroll
        for (int k = 0; k < 16; ++k) s += red[k * 64 + tid];
        out[tid] = s;
    }
}

extern "C" void kernel_launch(void* const* d_in, const int* in_sizes, int n_in,
                              void* d_out, int out_size, void* d_ws, size_t ws_size,
                              hipStream_t stream) {
    const int*   z       = (const int*)d_in[0];
    const float* pos     = (const float*)d_in[1];
    const int*   batch   = (const int*)d_in[2];
    const int*   ei      = (const int*)d_in[3];
    const float* emb     = (const float*)d_in[4];
    const float* lin_W   = (const float*)d_in[5];
    const float* mlp_W1  = (const float*)d_in[6];
    const float* mlp_b1  = (const float*)d_in[7];
    const float* mlp_W2  = (const float*)d_in[8];
    const float* mlp_b2  = (const float*)d_in[9];
    const float* v_W1    = (const float*)d_in[10];
    const float* v_b1    = (const float*)d_in[11];
    const float* v_W2    = (const float*)d_in[12];
    const float* v_b2    = (const float*)d_in[13];
    const float* u_W1    = (const float*)d_in[14];
    const float* u_b1    = (const float*)d_in[15];
    const float* u_W2    = (const float*)d_in[16];
    const float* u_b2    = (const float*)d_in[17];
    const int n  = in_sizes[0];
    const int E_ = in_sizes[3] / 2;
    float* out = (float*)d_out;

    char* wp = (char*)d_ws;
    auto alloc = [&](size_t bytes) { char* p = wp; wp += (bytes + 255) & ~(size_t)255; return p; };
    const int NB1K = (n + 1023) / 1024;
    const int NB256 = (n + 255) / 256;
    const int nchunk = (n + 15) / 16;
    unsigned short* vbf     = (unsigned short*)alloc((size_t)n * H * 2);
    unsigned short* vlinA   = (unsigned short*)alloc((size_t)n * H * 2);
    unsigned short* vlinB   = (unsigned short*)alloc((size_t)n * H * 2);
    unsigned short* WtAll   = (unsigned short*)alloc((size_t)18 * H * H * 2);
    unsigned short* Ut      = (unsigned short*)alloc((size_t)64 * H * 2);
    unsigned short* tbl     = (unsigned short*)alloc((size_t)6 * TB * H * 2);
    int*   eint    = (int*)alloc((size_t)E_ * 4);
    int2*  epack   = (int2*)alloc((size_t)E_ * 8);
    int*   deg     = (int*)alloc((size_t)n * 4);
    int*   sdeg    = (int*)alloc((size_t)n * 4);
    int*   perm    = (int*)alloc((size_t)n * 4);
    int*   iperm   = (int*)alloc((size_t)n * 4);
    int*   lrank   = (int*)alloc((size_t)n * 4);
    int*   row_ptr = (int*)alloc((size_t)(n + 1) * 4);
    int*   cursor  = (int*)alloc((size_t)n * 4);
    int*   bsum    = (int*)alloc((size_t)NB1K * 4);
    int*   bhist   = (int*)alloc((size_t)64 * NB256 * 4);
    int*   base    = (int*)alloc(64 * 4);
    float* partial = (float*)alloc((size_t)nchunk * 64 * 4);

    const float step = DMAX / TB;
    hipMemsetAsync(deg, 0, (size_t)n * 4, stream);

    prep_w_kernel<<<320, 256, 0, stream>>>(lin_W, v_W1, v_W2, u_W1, WtAll, Ut);
    table_all_kernel<<<384, 256, 0, stream>>>(mlp_W1, mlp_b1, mlp_W2, mlp_b2, tbl, step);
    edge_dist_kernel<<<(E_ + 255) / 256, 256, 0, stream>>>(ei, pos, eint, deg, E_, 1.0f / step);
    hist_pb_kernel<<<NB256, 256, 0, stream>>>(deg, bhist, lrank, n, NB256);
    scanb_kernel<<<1, 64, 0, stream>>>(bhist, base, NB256);
    place_kernel<<<NB256, 256, 0, stream>>>(deg, bhist, base, lrank, perm, iperm, sdeg, n, NB256);
    scanA_kernel<<<NB1K, 1024, 0, stream>>>(sdeg, bsum, n);
    scanC_kernel<<<NB1K, 1024, 0, stream>>>(sdeg, bsum, row_ptr, cursor, n);
    csr_fill_kernel<<<(E_ + 255) / 256, 256, 0, stream>>>(ei, eint, iperm, cursor, epack, E_);

    const int GRS = (nchunk + 3) / 4;
    gemm_rs_embed_kernel<<<GRS, 256, 0, stream>>>(z, perm, emb, WtAll, vbf, vlinA, n);
    unsigned short* cur = vlinA;
    unsigned short* nxt = vlinB;
    for (int l = 0; l < 6; ++l) {
        const unsigned short* W3t = (l < 5) ? (WtAll + (l + 1) * H * H) : nullptr;
        layer_kernel<<<nchunk, 256, 0, stream>>>(row_ptr, epack,
                                                 tbl + (size_t)l * TB * H, cur,
                                                 WtAll + (6 + l) * H * H,
                                                 WtAll + (12 + l) * H * H, W3t,
                                                 v_b1 + l * H, v_b2 + l * H,
                                                 vbf, nxt,
                                                 batch, perm, Ut, u_b1, u_W2, u_b2,
                                                 partial, n);
        unsigned short* tmp = cur; cur = nxt; nxt = tmp;
    }
    readout2_kernel<<<1, 1024, 0, stream>>>(partial, out, nchunk);
}